// Round 3
// baseline (1045.018 us; speedup 1.0000x reference)
//
#include <hip/hip_runtime.h>
#include <hip/hip_bf16.h>

// Problem constants
#define T_TOK 1024
#define H_DIM 2048
#define I_DIM 768
#define E_NUM 32
#define K_TOP 4
#define NPAIR (T_TOK * K_TOP)          // 4096 routed (token, expert) pairs
#define TM 32                          // tokens per m-tile
#define MAX_SLOTS (NPAIR + E_NUM * TM) // 5120 (worst-case padding)
#define MAX_TILES (NPAIR / TM + E_NUM) // 160

// ws layout (byte offsets)
#define WS_META   0                                   // int[512]
#define WS_TOKEN  2048                                // int[MAX_SLOTS]
#define WS_WEIGHT (WS_TOKEN + MAX_SLOTS * 4)          // float[MAX_SLOTS]
#define WS_HBUF   (WS_WEIGHT + MAX_SLOTS * 4)         // bf16[MAX_SLOTS][I_DIM]

typedef __bf16 bf16x8 __attribute__((ext_vector_type(8)));
typedef float f32x4 __attribute__((ext_vector_type(4)));
typedef float f32x8 __attribute__((ext_vector_type(8)));

__device__ inline bf16x8 cvt8(f32x8 v) {
    bf16x8 r;
#pragma unroll
    for (int i = 0; i < 8; ++i) r[i] = (__bf16)v[i];
    return r;
}

// ---------------------------------------------------------------------------
// Routing: group (token,k) pairs by expert, pad each expert to multiple of TM,
// build m-tile work queue. Single block.
// ---------------------------------------------------------------------------
__global__ void moe_route(const int* __restrict__ ids,
                          const float* __restrict__ ew,
                          int* __restrict__ meta,
                          int* __restrict__ slot_tok,
                          float* __restrict__ slot_w) {
    __shared__ int cnt[E_NUM], off[E_NUM], cur[E_NUM];
    __shared__ int s_tot;
    const int tid = threadIdx.x;
    if (tid < E_NUM) cnt[tid] = 0;
    __syncthreads();
    for (int p = tid; p < NPAIR; p += blockDim.x)
        atomicAdd(&cnt[ids[p]], 1);
    __syncthreads();
    if (tid == 0) {
        int tot = 0, nt = 0;
        for (int e = 0; e < E_NUM; ++e) {
            int pad = (cnt[e] + TM - 1) / TM * TM;
            off[e] = tot;
            for (int s = tot; s < tot + pad; s += TM) {
                meta[8 + nt] = e;
                meta[8 + MAX_TILES + nt] = s;
                ++nt;
            }
            tot += pad;
        }
        meta[0] = nt;
        meta[1] = tot;
        s_tot = tot;
    }
    __syncthreads();
    const int tot = s_tot;
    for (int s = tid; s < tot; s += blockDim.x) {
        slot_tok[s] = 0;     // padded slots point at token 0 with weight 0
        slot_w[s]   = 0.0f;
    }
    if (tid < E_NUM) cur[tid] = 0;
    __syncthreads();
    for (int p = tid; p < NPAIR; p += blockDim.x) {
        int e = ids[p];
        int i = atomicAdd(&cur[e], 1);
        int s = off[e] + i;
        slot_tok[s] = p / K_TOP;
        slot_w[s]   = ew[p];
    }
}

// ---------------------------------------------------------------------------
// Phase 1: h = silu(X Wg^T) * (X Wu^T) for each routed slot, expert-grouped.
// Work item = (m-tile of 32 slots) x (64-col chunk of I). Block = 4 waves;
// wave w covers cols [n0 + 16w, n0 + 16w + 16), two 16-row subtiles.
// Inputs fp32, converted to bf16 in-register for MFMA.
// ---------------------------------------------------------------------------
__global__ __launch_bounds__(256) void moe_gateup(
    const float* __restrict__ X,
    const float* __restrict__ Wg,
    const float* __restrict__ Wu,
    const int* __restrict__ meta,
    const int* __restrict__ slot_tok,
    __hip_bfloat16* __restrict__ Hb) {
    const int NCH = I_DIM / 64;  // 12
    const int nt = meta[0];
    const int n_items = nt * NCH;
    const int lane = threadIdx.x & 63;
    const int wave = threadIdx.x >> 6;
    const int col  = lane & 15;
    const int quad = lane >> 4;

    for (int item = blockIdx.x; item < n_items; item += gridDim.x) {
        const int tile = item / NCH;
        const int nch  = item - tile * NCH;
        const int e    = meta[8 + tile];
        const int s0   = meta[8 + MAX_TILES + tile];
        const int n0   = nch * 64 + wave * 16;

        const int t0 = slot_tok[s0 + col];
        const int t1 = slot_tok[s0 + 16 + col];
        const float* px0 = X + (size_t)t0 * H_DIM;
        const float* px1 = X + (size_t)t1 * H_DIM;
        const size_t wrow = ((size_t)e * I_DIM + n0 + col) * H_DIM;
        const float* pg = Wg + wrow;
        const float* pu = Wu + wrow;

        f32x4 ag0 = {0.f,0.f,0.f,0.f}, ag1 = {0.f,0.f,0.f,0.f};
        f32x4 au0 = {0.f,0.f,0.f,0.f}, au1 = {0.f,0.f,0.f,0.f};

        for (int k = quad * 8; k < H_DIM; k += 32) {
            bf16x8 a0 = cvt8(*(const f32x8*)(px0 + k));
            bf16x8 a1 = cvt8(*(const f32x8*)(px1 + k));
            bf16x8 bg = cvt8(*(const f32x8*)(pg + k));
            bf16x8 bu = cvt8(*(const f32x8*)(pu + k));
            ag0 = __builtin_amdgcn_mfma_f32_16x16x32_bf16(a0, bg, ag0, 0, 0, 0);
            ag1 = __builtin_amdgcn_mfma_f32_16x16x32_bf16(a1, bg, ag1, 0, 0, 0);
            au0 = __builtin_amdgcn_mfma_f32_16x16x32_bf16(a0, bu, au0, 0, 0, 0);
            au1 = __builtin_amdgcn_mfma_f32_16x16x32_bf16(a1, bu, au1, 0, 0, 0);
        }

#pragma unroll
        for (int r = 0; r < 4; ++r) {
            const int row = quad * 4 + r;
            float g0 = ag0[r], u0 = au0[r];
            float h0 = (g0 / (1.0f + __expf(-g0))) * u0;
            Hb[(size_t)(s0 + row) * I_DIM + n0 + col] = __float2bfloat16(h0);
            float g1 = ag1[r], u1 = au1[r];
            float h1 = (g1 / (1.0f + __expf(-g1))) * u1;
            Hb[(size_t)(s0 + 16 + row) * I_DIM + n0 + col] = __float2bfloat16(h1);
        }
    }
}

// ---------------------------------------------------------------------------
// Phase 2: y[t] += w * (h @ Wd^T), atomically accumulated into fp32 d_out.
// Work item = (m-tile) x (64-col chunk of H).
// ---------------------------------------------------------------------------
__global__ __launch_bounds__(256) void moe_down(
    const float* __restrict__ Wd,
    const int* __restrict__ meta,
    const int* __restrict__ slot_tok,
    const float* __restrict__ slot_w,
    const __hip_bfloat16* __restrict__ Hb,
    float* __restrict__ Y) {
    const int NCH = H_DIM / 64;  // 32
    const int nt = meta[0];
    const int n_items = nt * NCH;
    const int lane = threadIdx.x & 63;
    const int wave = threadIdx.x >> 6;
    const int col  = lane & 15;
    const int quad = lane >> 4;

    for (int item = blockIdx.x; item < n_items; item += gridDim.x) {
        const int tile = item / NCH;
        const int nch  = item - tile * NCH;
        const int e    = meta[8 + tile];
        const int s0   = meta[8 + MAX_TILES + tile];
        const int n0   = nch * 64 + wave * 16;

        const __hip_bfloat16* ph0 = Hb + (size_t)(s0 + col) * I_DIM;
        const __hip_bfloat16* ph1 = Hb + (size_t)(s0 + 16 + col) * I_DIM;
        const float* pd = Wd + ((size_t)e * H_DIM + n0 + col) * I_DIM;

        f32x4 a0 = {0.f,0.f,0.f,0.f}, a1 = {0.f,0.f,0.f,0.f};

        for (int k = quad * 8; k < I_DIM; k += 32) {
            bf16x8 h0 = *(const bf16x8*)(const void*)(ph0 + k);
            bf16x8 h1 = *(const bf16x8*)(const void*)(ph1 + k);
            bf16x8 b  = cvt8(*(const f32x8*)(pd + k));
            a0 = __builtin_amdgcn_mfma_f32_16x16x32_bf16(h0, b, a0, 0, 0, 0);
            a1 = __builtin_amdgcn_mfma_f32_16x16x32_bf16(h1, b, a1, 0, 0, 0);
        }

#pragma unroll
        for (int r = 0; r < 4; ++r) {
            const int row = quad * 4 + r;
            const int sA = s0 + row;
            atomicAdd(&Y[(size_t)slot_tok[sA] * H_DIM + n0 + col], a0[r] * slot_w[sA]);
            const int sB = s0 + 16 + row;
            atomicAdd(&Y[(size_t)slot_tok[sB] * H_DIM + n0 + col], a1[r] * slot_w[sB]);
        }
    }
}

extern "C" void kernel_launch(void* const* d_in, const int* in_sizes, int n_in,
                              void* d_out, int out_size, void* d_ws, size_t ws_size,
                              hipStream_t stream) {
    const float* X  = (const float*)d_in[0];
    const float* Wg = (const float*)d_in[1];
    const float* Wu = (const float*)d_in[2];
    const float* Wd = (const float*)d_in[3];
    const int* ids  = (const int*)d_in[4];
    const float* ew = (const float*)d_in[5];

    char* ws = (char*)d_ws;
    int*   meta     = (int*)(ws + WS_META);
    int*   slot_tok = (int*)(ws + WS_TOKEN);
    float* slot_w   = (float*)(ws + WS_WEIGHT);
    __hip_bfloat16* Hb = (__hip_bfloat16*)(ws + WS_HBUF);
    float* Y = (float*)d_out;  // fp32 output (reference returns float32)

    // d_out is re-poisoned before every timed launch — zero it ourselves.
    hipMemsetAsync(Y, 0, (size_t)T_TOK * H_DIM * sizeof(float), stream);
    moe_route<<<1, 256, 0, stream>>>(ids, ew, meta, slot_tok, slot_w);
    moe_gateup<<<1920, 256, 0, stream>>>(X, Wg, Wu, meta, slot_tok, Hb);
    moe_down<<<5120, 256, 0, stream>>>(Wd, meta, slot_tok, slot_w, Hb, Y);
}